// Round 13
// baseline (194.746 us; speedup 1.0000x reference)
//
#include <hip/hip_runtime.h>

// LSTM text classifier: emb-gather -> LSTM(512 steps) -> FC(32->2)
//   R13: fanout-free dot. Five engines (readlane / pk_fma+SGPR / wave-DPP /
//   ds_swizzle / f16 dot2) all converged at ~420-445 busy cyc/step because
//   every SEPARATE cross-lane op costs ~4cyc x 32 slots. Fix: fuse the lane
//   rotation INTO the FMA via the DPP src modifier (row_ror:1..15, rotates
//   within 16-lane rows). Layout: lane (m=l&15,q=l>>4) owns rows q*32+m and
//   q*32+m+16; hL=h_m,hH=h_{m+16} periodic-16 -> row-local DPP suffices.
//   64 v_fmac_f32_dpp, ZERO fanout instructions. Direction runtime-probed.
//   Tail = R12's EX4 (verified) in f32. waves_per_eu(1,1) kept (R6).

#define LOG2E 1.44269504088896340736f

typedef float f32x2 __attribute__((ext_vector_type(2)));
typedef unsigned uv2 __attribute__((ext_vector_type(2)));
typedef float f32x16 __attribute__((ext_vector_type(16)));
typedef float f32x32 __attribute__((ext_vector_type(32)));

__device__ __forceinline__ float fast_rcp(float x) { return __builtin_amdgcn_rcpf(x); }
__device__ __forceinline__ float fast_exp2(float x) { return __builtin_amdgcn_exp2f(x); }

// 16-block swap, dual outputs; ordering resolved by runtime probe (ok16)
__device__ __forceinline__ uv2 p16swap(unsigned x) {
#if __has_builtin(__builtin_amdgcn_permlane16_swap)
    return __builtin_amdgcn_permlane16_swap(x, x, false, false);
#else
    unsigned other = (unsigned)__shfl_xor((int)x, 16, 64);
    uv2 r;
    if (threadIdx.x & 16) { r.x = other; r.y = x; }
    else                  { r.x = x;     r.y = other; }
    return r;
#endif
}

// fused rotate+FMA: ACC += DPP_row_ror_J(H) * W   (J = 1..15 literal)
#define FMACDPP(ACC, H, W, J)                                                  \
    asm("v_fmac_f32_dpp %0, %1, %2 row_ror:" #J " row_mask:0xf bank_mask:0xf"  \
        : "+v"(ACC)                                                            \
        : "v"(H), "v"(W));

// ---------------- K1: projected + prescaled embedding table ----------------
// Layout: lane (m,q) -> float2 { proj[q*32+m], proj[q*32+m+16] } * s_q
__global__ __launch_bounds__(64, 1) void build_ptab(
    const float4* __restrict__ emb4, const float4* __restrict__ wih4,
    const float* __restrict__ bih, const float* __restrict__ bhh,
    float2* __restrict__ ptab, int nrows) {
    const int lane = threadIdx.x;
    const int m = lane & 15, q = lane >> 4;
    const int r0 = q * 32 + m, r1 = r0 + 16;
    const float sq = (q == 2) ? (2.0f * LOG2E) : (-LOG2E);

    float w0[32], w1[32];
#pragma unroll
    for (int t = 0; t < 8; ++t) {
        float4 a = wih4[r0 * 8 + t];
        float4 b = wih4[r1 * 8 + t];
        w0[4 * t + 0] = a.x; w0[4 * t + 1] = a.y; w0[4 * t + 2] = a.z; w0[4 * t + 3] = a.w;
        w1[4 * t + 0] = b.x; w1[4 * t + 1] = b.y; w1[4 * t + 2] = b.z; w1[4 * t + 3] = b.w;
    }
    const float bias0 = bih[r0] + bhh[r0];
    const float bias1 = bih[r1] + bhh[r1];

    for (int v = blockIdx.x; v < nrows; v += gridDim.x) {
        float a0 = bias0, a1 = bias1;
#pragma unroll
        for (int t = 0; t < 8; ++t) {
            float4 e = emb4[v * 8 + t];  // wave-uniform -> cache broadcast
            a0 = fmaf(e.x, w0[4 * t + 0], a0);
            a0 = fmaf(e.y, w0[4 * t + 1], a0);
            a0 = fmaf(e.z, w0[4 * t + 2], a0);
            a0 = fmaf(e.w, w0[4 * t + 3], a0);
            a1 = fmaf(e.x, w1[4 * t + 0], a1);
            a1 = fmaf(e.y, w1[4 * t + 1], a1);
            a1 = fmaf(e.z, w1[4 * t + 2], a1);
            a1 = fmaf(e.w, w1[4 * t + 3], a1);
        }
        ptab[v * 64 + lane] = make_float2(a0 * sq, a1 * sq);  // coalesced 512B/row
    }
}

#define REP15(M) M(1) M(2) M(3) M(4) M(5) M(6) M(7) M(8) M(9) M(10) M(11)      \
    M(12) M(13) M(14) M(15)

// slot J (J=1..15): 4 fused rotate-FMAs, constant vector indices
#define DOTJ(J)                                                                \
    FMACDPP(_a0p, hL, wa[J], J)                                                \
    FMACDPP(_a0q, hH, wb[J], J)                                                \
    FMACDPP(_a1p, hL, wc[J], J)                                                \
    FMACDPP(_a1q, hH, wd[J], J)

// deliver one cell-value's 4 gate types to all lanes (verified R12):
// p16swap splits even/odd 16-blocks (probe ok16), perm32 broadcasts halves.
#define EX4(V, I_, F_, G_, O_)                                                 \
    {                                                                          \
        uv2 _t = p16swap(__float_as_uint(V));                                  \
        unsigned _Eu = ok16 ? _t.x : _t.y; /* even block: i (lo) / g (hi) */   \
        unsigned _Ou = ok16 ? _t.y : _t.x; /* odd  block: f (lo) / o (hi) */   \
        uv2 _s = __builtin_amdgcn_permlane32_swap(_Eu, _Eu, false, false);     \
        uv2 _u = __builtin_amdgcn_permlane32_swap(_Ou, _Ou, false, false);     \
        I_ = __uint_as_float(_s.x); G_ = __uint_as_float(_s.y);                \
        F_ = __uint_as_float(_u.x); O_ = __uint_as_float(_u.y);                \
    }

// one LSTM step; P = f32x2 {proj row r0, proj row r1} (prescaled by s_q).
// State: hL=h_m, hH=h_{m+16}, cL, cH - all periodic-16 across the wave.
#define STEP(P)                                                                \
    do {                                                                       \
        float _a0p = fmaf(hL, wa[0], (P).x);                                   \
        float _a0q = hH * wb[0];                                               \
        float _a1p = fmaf(hL, wc[0], (P).y);                                   \
        float _a1q = hH * wd[0];                                               \
        REP15(DOTJ)                                                            \
        float _A0 = _a0p + _a0q; /* preact*s_q, row r0 (cell m)    */          \
        float _A1 = _a1p + _a1q; /* preact*s_q, row r1 (cell m+16) */          \
        float _RL = fast_rcp(1.0f + fast_exp2(_A0));                           \
        float _RH = fast_rcp(1.0f + fast_exp2(_A1));                           \
        float _vL = fmaf(kq, _RL, bq); /* own-type gate, cell m    */          \
        float _vH = fmaf(kq, _RH, bq); /* own-type gate, cell m+16 */          \
        float _iL, _fL, _gL, _oL, _iH, _fH, _gH, _oH;                          \
        EX4(_vL, _iL, _fL, _gL, _oL)                                           \
        EX4(_vH, _iH, _fH, _gH, _oH)                                           \
        cL = fmaf(_fL, cL, _iL * _gL);                                         \
        cH = fmaf(_fH, cH, _iH * _gH);                                         \
        float _TL = fmaf(-2.0f, fast_rcp(1.0f + fast_exp2(cL * (2.0f * LOG2E))), 1.0f); \
        float _TH = fmaf(-2.0f, fast_rcp(1.0f + fast_exp2(cH * (2.0f * LOG2E))), 1.0f); \
        hL = _oL * _TL;                                                        \
        hH = _oH * _TH;                                                        \
    } while (0)

// ---------------- K2: LSTM scan, one wave per batch element ----------------
template <bool PTAB>
__global__ __launch_bounds__(64)
__attribute__((amdgpu_waves_per_eu(1, 1)))  // pressure target = 1 wave/EU (R6, verified)
void lstm_scan(
    const int* __restrict__ x,
    const float2* __restrict__ ptab,
    const float* __restrict__ emb,
    const float* __restrict__ wih,
    const float* __restrict__ bih,
    const float* __restrict__ bhh,
    const float* __restrict__ whh,
    const float* __restrict__ fcw,
    const float* __restrict__ fcb,
    float* __restrict__ out,
    int S) {
    extern __shared__ int xrow[];
    const int b = blockIdx.x;
    const int lane = threadIdx.x;
    const int m = lane & 15, q = lane >> 4;
    const int r0 = q * 32 + m, r1 = r0 + 16;
    const float sq = (q == 2) ? (2.0f * LOG2E) : (-LOG2E);
    const float kq = (q == 2) ? -2.0f : 1.0f;  // v = kq*R + bq: sigmoid=R, tanh=1-2R
    const float bq = (q == 2) ? 1.0f : 0.0f;

    // token ids in LDS, padded so the prefetch ring never reads OOB
    for (int i = lane; i < S + 16; i += 64) xrow[i] = (i < S) ? x[(size_t)b * S + i] : 0;
    __syncthreads();

    // probe row_ror:1 receive direction (wave-uniform): after ror:j, lane m
    // receives h from lane (m + delta*j)&15
    int delta;
    {
        int g = __builtin_amdgcn_mov_dpp(lane, 0x121, 0xF, 0xF, true);
        delta = ((g & 15) - m) & 15;  // 1 or 15
    }
    // probe p16swap output ordering (verified pattern, R12)
    bool ok16;
    {
        uv2 t = p16swap((unsigned)lane);
        ok16 = (t.x == (unsigned)(lane & ~16));
    }

    // recurrent weights, rotation-matched, prescaled:
    //   slot j pairs with row_ror:j -> col (m + delta*j)&15 (lo) / +16 (hi)
    f32x16 wa, wb, wc, wd;
    {
        const int r0w = r0 * 32, r1w = r1 * 32;
#pragma unroll
        for (int j = 0; j < 16; ++j) {
            int cj = (m + delta * j) & 15;
            wa[j] = whh[r0w + cj] * sq;
            wb[j] = whh[r0w + 16 + cj] * sq;
            wc[j] = whh[r1w + cj] * sq;
            wd[j] = whh[r1w + 16 + cj] * sq;
        }
    }

    float hL = 0.0f, hH = 0.0f, cL = 0.0f, cH = 0.0f;  // periodic-16

    if constexpr (PTAB) {
        const char* pb = (const char*)ptab + (unsigned)(lane << 3);
        int i0 = xrow[4], i1 = xrow[5], i2 = xrow[6], i3 = xrow[7];
        f32x2 p0 = *(const f32x2*)(pb + ((unsigned)xrow[0] << 9));
        f32x2 p1 = *(const f32x2*)(pb + ((unsigned)xrow[1] << 9));
        f32x2 p2 = *(const f32x2*)(pb + ((unsigned)xrow[2] << 9));
        f32x2 p3 = *(const f32x2*)(pb + ((unsigned)xrow[3] << 9));
        int t = 0;
        for (; t + 8 <= S; t += 4) {
            STEP(p0); p0 = *(const f32x2*)(pb + ((unsigned)i0 << 9)); i0 = xrow[t + 8];
            STEP(p1); p1 = *(const f32x2*)(pb + ((unsigned)i1 << 9)); i1 = xrow[t + 9];
            STEP(p2); p2 = *(const f32x2*)(pb + ((unsigned)i2 << 9)); i2 = xrow[t + 10];
            STEP(p3); p3 = *(const f32x2*)(pb + ((unsigned)i3 << 9)); i3 = xrow[t + 11];
        }
        if (t + 0 < S) STEP(p0);
        if (t + 1 < S) STEP(p1);
        if (t + 2 < S) STEP(p2);
        if (t + 3 < S) STEP(p3);
        if (t + 4 < S) { f32x2 qq = *(const f32x2*)(pb + ((unsigned)i0 << 9)); STEP(qq); }
        if (t + 5 < S) { f32x2 qq = *(const f32x2*)(pb + ((unsigned)i1 << 9)); STEP(qq); }
        if (t + 6 < S) { f32x2 qq = *(const f32x2*)(pb + ((unsigned)i2 << 9)); STEP(qq); }
    } else {
        // fallback: on-the-fly input projection, same (m,q) layout; cold path
        f32x32 wi0, wi1;
        {
            const float4* wih4 = (const float4*)wih;
#pragma unroll
            for (int t = 0; t < 8; ++t) {
                float4 a = wih4[r0 * 8 + t];
                float4 bb = wih4[r1 * 8 + t];
                wi0[4 * t + 0] = a.x * sq; wi0[4 * t + 1] = a.y * sq;
                wi0[4 * t + 2] = a.z * sq; wi0[4 * t + 3] = a.w * sq;
                wi1[4 * t + 0] = bb.x * sq; wi1[4 * t + 1] = bb.y * sq;
                wi1[4 * t + 2] = bb.z * sq; wi1[4 * t + 3] = bb.w * sq;
            }
        }
        const float bias0 = (bih[r0] + bhh[r0]) * sq;
        const float bias1 = (bih[r1] + bhh[r1]) * sq;
        const float4* emb4 = (const float4*)emb;
        for (int t = 0; t < S; ++t) {
            int idx = xrow[t];
            float a0 = bias0, a1 = bias1;
#pragma unroll
            for (int u = 0; u < 8; ++u) {
                float4 e = emb4[(size_t)idx * 8 + u];
                a0 = fmaf(e.x, wi0[4 * u + 0], a0);
                a0 = fmaf(e.y, wi0[4 * u + 1], a0);
                a0 = fmaf(e.z, wi0[4 * u + 2], a0);
                a0 = fmaf(e.w, wi0[4 * u + 3], a0);
                a1 = fmaf(e.x, wi1[4 * u + 0], a1);
                a1 = fmaf(e.y, wi1[4 * u + 1], a1);
                a1 = fmaf(e.z, wi1[4 * u + 2], a1);
                a1 = fmaf(e.w, wi1[4 * u + 3], a1);
            }
            f32x2 _p; _p.x = a0; _p.y = a1;
            STEP(_p);
        }
    }

    // FC: lane holds h for cells m, m+16; use lanes 0..15 only (q=0)
    float w0a = fcw[m], w0b = fcw[16 + m];
    float w1a = fcw[32 + m], w1b = fcw[48 + m];
    float p0v = (lane < 16) ? fmaf(hL, w0a, hH * w0b) : 0.0f;
    float p1v = (lane < 16) ? fmaf(hL, w1a, hH * w1b) : 0.0f;
#pragma unroll
    for (int mm = 32; mm >= 1; mm >>= 1) {
        p0v += __shfl_xor(p0v, mm, 64);
        p1v += __shfl_xor(p1v, mm, 64);
    }
    if (lane == 0) {
        out[b * 2 + 0] = p0v + fcb[0];
        out[b * 2 + 1] = p1v + fcb[1];
    }
}

extern "C" void kernel_launch(void* const* d_in, const int* in_sizes, int n_in,
                              void* d_out, int out_size, void* d_ws, size_t ws_size,
                              hipStream_t stream) {
    const int* x = (const int*)d_in[0];
    const float* emb = (const float*)d_in[1];
    const float* wih = (const float*)d_in[2];
    const float* whh = (const float*)d_in[3];
    const float* bih = (const float*)d_in[4];
    const float* bhh = (const float*)d_in[5];
    const float* fcw = (const float*)d_in[6];
    const float* fcb = (const float*)d_in[7];
    float* out = (float*)d_out;

    const int B = out_size / 2;          // 1024
    const int S = in_sizes[0] / B;       // 512
    const int nrows = in_sizes[1] / 32;  // 50001 (EMB=32)

    const size_t need = (size_t)nrows * 64 * sizeof(float2);  // 25.6 MB
    const size_t smem = (size_t)(S + 16) * sizeof(int);

    if (ws_size >= need) {
        float2* ptab = (float2*)d_ws;
        int nb = nrows < 8192 ? nrows : 8192;
        build_ptab<<<nb, 64, 0, stream>>>((const float4*)emb, (const float4*)wih,
                                          bih, bhh, ptab, nrows);
        lstm_scan<true><<<B, 64, smem, stream>>>(x, ptab, emb, wih, bih, bhh, whh,
                                                 fcw, fcb, out, S);
    } else {
        lstm_scan<false><<<B, 64, smem, stream>>>(x, nullptr, emb, wih, bih, bhh, whh,
                                                  fcw, fcb, out, S);
    }
}

// Round 14
// 143.850 us; speedup vs baseline: 1.3538x; 1.3538x over previous
//
#include <hip/hip_runtime.h>

// LSTM text classifier: emb-gather -> LSTM(512 steps) -> FC(32->2)
//   R14 = R10 (best, 139us total) with the dot's serial DPP chain split 16->8:
//   4 chains {ROR(h)x8, ROL(h)x8, ROR(h16)x7, ROL(h16)x7}, h16 = xor16 of the
//   periodic-32 h via one permlane16_swap + cndmask (machinery verified R12).
//   Six engines (R6/R8/R9/R10/R12/R13) all measured ~423-490 busy cyc/step ->
//   issue floor is structural (cross-lane ~4cyc/op x32 + 64 FMA). This round
//   attacks the wall-busy gap (~200cyc serial latency): halve DPP chain depth.
//   Everything else verbatim R10 (tail bcast_both+cs, probes, ring, (1,1)).

#define LOG2E 1.44269504088896340736f

typedef float f32x2 __attribute__((ext_vector_type(2)));
typedef unsigned uv2 __attribute__((ext_vector_type(2)));
typedef float f32x8 __attribute__((ext_vector_type(8)));
typedef float f32x32 __attribute__((ext_vector_type(32)));

__device__ __forceinline__ float fast_rcp(float x) { return __builtin_amdgcn_rcpf(x); }
__device__ __forceinline__ float fast_exp2(float x) { return __builtin_amdgcn_exp2f(x); }

// permlane32_swap(x,x): r.x = lo-half value in ALL lanes, r.y = hi-half value
// in ALL lanes. HW-verified (R8-R12, absmax 0.0).
__device__ __forceinline__ f32x2 bcast_both(float x) {
    uv2 r = __builtin_amdgcn_permlane32_swap(__float_as_uint(x), __float_as_uint(x),
                                             false, false);
    f32x2 o;
    o.x = __uint_as_float(r.x);
    o.y = __uint_as_float(r.y);
    return o;
}

// 16-block swap, dual outputs; ordering resolved by runtime probe (verified R12)
__device__ __forceinline__ uv2 p16swap(unsigned x) {
#if __has_builtin(__builtin_amdgcn_permlane16_swap)
    return __builtin_amdgcn_permlane16_swap(x, x, false, false);
#else
    unsigned other = (unsigned)__shfl_xor((int)x, 16, 64);
    uv2 r;
    if (threadIdx.x & 16) { r.x = other; r.y = x; }
    else                  { r.x = x;     r.y = other; }
    return r;
#endif
}

// wave rotate-by-1 DPP, both directions (verified R10, absmax 0, runtime probed)
#define ROTA(V) __int_as_float(__builtin_amdgcn_mov_dpp(__float_as_int(V), 0x13C, 0xF, 0xF, true))
#define ROTB(V) __int_as_float(__builtin_amdgcn_mov_dpp(__float_as_int(V), 0x134, 0xF, 0xF, true))

// ---------------- K1: projected + prescaled embedding table ----------------
__global__ __launch_bounds__(64, 1) void build_ptab(
    const float4* __restrict__ emb4, const float4* __restrict__ wih4,
    const float* __restrict__ bih, const float* __restrict__ bhh,
    float2* __restrict__ ptab, int nrows) {
    const int lane = threadIdx.x;

    float w0[32], w1[32];
#pragma unroll
    for (int q = 0; q < 8; ++q) {
        float4 a = wih4[lane * 8 + q];
        float4 b = wih4[(lane + 64) * 8 + q];
        w0[4 * q + 0] = a.x; w0[4 * q + 1] = a.y; w0[4 * q + 2] = a.z; w0[4 * q + 3] = a.w;
        w1[4 * q + 0] = b.x; w1[4 * q + 1] = b.y; w1[4 * q + 2] = b.z; w1[4 * q + 3] = b.w;
    }
    const float bias0 = bih[lane] + bhh[lane];
    const float bias1 = bih[lane + 64] + bhh[lane + 64];
    const float s0 = -LOG2E;                                   // rows l: i,f -> sigmoid
    const float s1 = (lane < 32) ? (2.0f * LOG2E) : (-LOG2E);  // rows l+64: g tanh / o sigmoid

    for (int v = blockIdx.x; v < nrows; v += gridDim.x) {
        float a0 = bias0, a1 = bias1;
#pragma unroll
        for (int q = 0; q < 8; ++q) {
            float4 e = emb4[v * 8 + q];  // wave-uniform -> cache broadcast
            a0 = fmaf(e.x, w0[4 * q + 0], a0);
            a0 = fmaf(e.y, w0[4 * q + 1], a0);
            a0 = fmaf(e.z, w0[4 * q + 2], a0);
            a0 = fmaf(e.w, w0[4 * q + 3], a0);
            a1 = fmaf(e.x, w1[4 * q + 0], a1);
            a1 = fmaf(e.y, w1[4 * q + 1], a1);
            a1 = fmaf(e.z, w1[4 * q + 2], a1);
            a1 = fmaf(e.w, w1[4 * q + 3], a1);
        }
        ptab[v * 64 + lane] = make_float2(a0 * s0, a1 * s1);  // coalesced 512B/row
    }
}

// one LSTM step; P = packed {g0,g1} prescaled pre-activations.
// Uses kernel-scope h, cs, useX, wI0,wI1, A0,A1,B0,B1,C0,C1,D0,D1.
// h, cs valid in ALL 64 lanes (periodic-32); cs = c * 2*log2e.
// Dot: identity + 4 chains (depth <= 8): ROR/ROL from h, ROR/ROL from h16.
#define STEP(P)                                                                \
    do {                                                                       \
        float _a0 = fmaf(h, wI0, (P).x);                                       \
        float _b0 = fmaf(h, wI1, (P).y);                                       \
        uv2 _sw = p16swap(__float_as_uint(h));                                 \
        float _h16 = __uint_as_float(useX ? _sw.x : _sw.y);                    \
        float _a1 = 0.f, _b1 = 0.f, _a2 = 0.f, _b2 = 0.f, _a3 = 0.f, _b3 = 0.f;\
        float _hA = h, _hB = h, _hC = _h16, _hD = _h16;                        \
        _a0 = fmaf(_h16, C0[0], _a0);                                          \
        _b0 = fmaf(_h16, C1[0], _b0);                                          \
        _Pragma("unroll") for (int _j = 0; _j < 7; ++_j) {                     \
            _hA = ROTA(_hA);                                                   \
            _a1 = fmaf(_hA, A0[_j], _a1); _b1 = fmaf(_hA, A1[_j], _b1);        \
            _hB = ROTB(_hB);                                                   \
            _a2 = fmaf(_hB, B0[_j], _a2); _b2 = fmaf(_hB, B1[_j], _b2);        \
            _hC = ROTA(_hC);                                                   \
            _a0 = fmaf(_hC, C0[_j + 1], _a0); _b0 = fmaf(_hC, C1[_j + 1], _b0);\
            _hD = ROTB(_hD);                                                   \
            _a3 = fmaf(_hD, D0[_j], _a3); _b3 = fmaf(_hD, D1[_j], _b3);        \
        }                                                                      \
        _hA = ROTA(_hA);                                                       \
        _a1 = fmaf(_hA, A0[7], _a1); _b1 = fmaf(_hA, A1[7], _b1);              \
        _hB = ROTB(_hB);                                                       \
        _a2 = fmaf(_hB, B0[7], _a2); _b2 = fmaf(_hB, B1[7], _b2);              \
        float _A0 = (_a0 + _a1) + (_a2 + _a3); /* lo: y_i*s0, hi: y_f*s0 */    \
        float _A1 = (_b0 + _b1) + (_b2 + _b3); /* lo: y_g*s1, hi: y_o*s1 */    \
        float _sg = fast_rcp(1.0f + fast_exp2(_A0)); /* lo:i  hi:f */          \
        float _r1 = fast_rcp(1.0f + fast_exp2(_A1)); /* lo:gf hi:o */          \
        f32x2 _bs = bcast_both(_sg); /* .x=i .y=f (all lanes) */               \
        f32x2 _br = bcast_both(_r1); /* .x=gf .y=o (all lanes) */              \
        float _ggs = fmaf(-4.0f * LOG2E, _br.x, 2.0f * LOG2E); /* tanh(g)*2log2e */ \
        cs = fmaf(_bs.y, cs, _bs.x * _ggs);                                    \
        h = _br.y * fmaf(-2.0f, fast_rcp(1.0f + fast_exp2(cs)), 1.0f);         \
    } while (0)

// ---------------- K2: LSTM scan, one wave per batch element ----------------
template <bool PTAB>
__global__ __launch_bounds__(64)
__attribute__((amdgpu_waves_per_eu(1, 1)))  // pressure target = 1 wave/EU (R6, verified)
void lstm_scan(
    const int* __restrict__ x,
    const float2* __restrict__ ptab,
    const float* __restrict__ emb,
    const float* __restrict__ wih,
    const float* __restrict__ bih,
    const float* __restrict__ bhh,
    const float* __restrict__ whh,
    const float* __restrict__ fcw,
    const float* __restrict__ fcb,
    float* __restrict__ out,
    int S) {
    extern __shared__ int xrow[];
    const int b = blockIdx.x;
    const int lane = threadIdx.x;

    // token ids in LDS, padded so the prefetch ring never reads OOB
    for (int i = lane; i < S + 16; i += 64) xrow[i] = (i < S) ? x[(size_t)b * S + i] : 0;
    __syncthreads();

    const float s0 = -LOG2E;
    const float s1 = (lane < 32) ? (2.0f * LOG2E) : (-LOG2E);

    // probe both wave-rotate directions (verified R10)
    int dirA, dirB;
    {
        int gA = __builtin_amdgcn_mov_dpp(lane, 0x13C, 0xF, 0xF, true);
        dirA = (gA == ((lane + 1) & 63)) ? 1 : -1;
        int gB = __builtin_amdgcn_mov_dpp(lane, 0x134, 0xF, 0xF, true);
        dirB = (gB == ((lane + 63) & 63)) ? -1 : 1;
    }
    // probe p16swap output ordering (verified R12): with V=lane,
    // t.x == lane&~16 means t.x carries the LOWER 16-group's value.
    bool ok16;
    {
        uv2 t = p16swap((unsigned)lane);
        ok16 = (t.x == (unsigned)(lane & ~16));
    }
    // value from lane^16: upper-group lanes take the lower-group output and
    // vice versa; useX folds the probe into one hoisted bool.
    const bool useX = ((lane & 16) != 0) == ok16;

    // recurrent weights, chain-matched, prescaled. Rows: r0=lane, r1=lane+64.
    //   identity: col lane&31
    //   A[j] (ROR from h,  j=0..7): col (lane + dirA*(j+1)) & 31
    //   B[j] (ROL from h,  j=0..7): col (lane + dirB*(j+1)) & 31
    //   C[k] (ROR from h16,k=0..7): col (lane + 16 + dirA*k) & 31
    //   D[k] (ROL from h16,k=1..7): col (lane + 16 + dirB*k) & 31 (D[7] pad)
    float wI0, wI1;
    f32x8 A0, A1, B0, B1, C0, C1, D0, D1;
    {
        const int r0w = lane * 32;
        const int r1w = (lane + 64) * 32;
        wI0 = whh[r0w + (lane & 31)] * s0;
        wI1 = whh[r1w + (lane & 31)] * s1;
#pragma unroll
        for (int j = 0; j < 8; ++j) {
            int cA = (lane + dirA * (j + 1)) & 31;
            int cB = (lane + dirB * (j + 1)) & 31;
            int cC = (lane + 16 + dirA * j) & 31;
            A0[j] = whh[r0w + cA] * s0;
            A1[j] = whh[r1w + cA] * s1;
            B0[j] = whh[r0w + cB] * s0;
            B1[j] = whh[r1w + cB] * s1;
            C0[j] = whh[r0w + cC] * s0;
            C1[j] = whh[r1w + cC] * s1;
        }
#pragma unroll
        for (int k = 1; k < 8; ++k) {
            int cD = (lane + 16 + dirB * k) & 31;
            D0[k - 1] = whh[r0w + cD] * s0;
            D1[k - 1] = whh[r1w + cD] * s1;
        }
        D0[7] = 0.0f;
        D1[7] = 0.0f;
    }

    float h = 0.0f, cs = 0.0f;  // valid in all 64 lanes (periodic-32); cs = c*2log2e

    if constexpr (PTAB) {
        const char* pb = (const char*)ptab + (unsigned)(lane << 3);
        int i0 = xrow[4], i1 = xrow[5], i2 = xrow[6], i3 = xrow[7];
        f32x2 p0 = *(const f32x2*)(pb + ((unsigned)xrow[0] << 9));
        f32x2 p1 = *(const f32x2*)(pb + ((unsigned)xrow[1] << 9));
        f32x2 p2 = *(const f32x2*)(pb + ((unsigned)xrow[2] << 9));
        f32x2 p3 = *(const f32x2*)(pb + ((unsigned)xrow[3] << 9));
        int t = 0;
        for (; t + 8 <= S; t += 4) {
            STEP(p0); p0 = *(const f32x2*)(pb + ((unsigned)i0 << 9)); i0 = xrow[t + 8];
            STEP(p1); p1 = *(const f32x2*)(pb + ((unsigned)i1 << 9)); i1 = xrow[t + 9];
            STEP(p2); p2 = *(const f32x2*)(pb + ((unsigned)i2 << 9)); i2 = xrow[t + 10];
            STEP(p3); p3 = *(const f32x2*)(pb + ((unsigned)i3 << 9)); i3 = xrow[t + 11];
        }
        if (t + 0 < S) STEP(p0);
        if (t + 1 < S) STEP(p1);
        if (t + 2 < S) STEP(p2);
        if (t + 3 < S) STEP(p3);
        if (t + 4 < S) { f32x2 q = *(const f32x2*)(pb + ((unsigned)i0 << 9)); STEP(q); }
        if (t + 5 < S) { f32x2 q = *(const f32x2*)(pb + ((unsigned)i1 << 9)); STEP(q); }
        if (t + 6 < S) { f32x2 q = *(const f32x2*)(pb + ((unsigned)i2 << 9)); STEP(q); }
    } else {
        // fallback: on-the-fly input projection (workspace too small); cold path
        f32x32 wi0, wi1;
        {
            const float4* wih4 = (const float4*)wih;
#pragma unroll
            for (int q = 0; q < 8; ++q) {
                float4 a = wih4[lane * 8 + q];
                float4 bb = wih4[(lane + 64) * 8 + q];
                wi0[4 * q + 0] = a.x * s0; wi0[4 * q + 1] = a.y * s0;
                wi0[4 * q + 2] = a.z * s0; wi0[4 * q + 3] = a.w * s0;
                wi1[4 * q + 0] = bb.x * s1; wi1[4 * q + 1] = bb.y * s1;
                wi1[4 * q + 2] = bb.z * s1; wi1[4 * q + 3] = bb.w * s1;
            }
        }
        const float bias0 = (bih[lane] + bhh[lane]) * s0;
        const float bias1 = (bih[lane + 64] + bhh[lane + 64]) * s1;
        const float4* emb4 = (const float4*)emb;
        for (int t = 0; t < S; ++t) {
            int idx = xrow[t];
            float a0 = bias0, a1 = bias1;
#pragma unroll
            for (int q = 0; q < 8; ++q) {
                float4 e = emb4[(size_t)idx * 8 + q];
                a0 = fmaf(e.x, wi0[4 * q + 0], a0);
                a0 = fmaf(e.y, wi0[4 * q + 1], a0);
                a0 = fmaf(e.z, wi0[4 * q + 2], a0);
                a0 = fmaf(e.w, wi0[4 * q + 3], a0);
                a1 = fmaf(e.x, wi1[4 * q + 0], a1);
                a1 = fmaf(e.y, wi1[4 * q + 1], a1);
                a1 = fmaf(e.z, wi1[4 * q + 2], a1);
                a1 = fmaf(e.w, wi1[4 * q + 3], a1);
            }
            f32x2 _p; _p.x = a0; _p.y = a1;
            STEP(_p);
        }
    }

    // FC: out[b][n] = sum_k h_k * fc_w[n][k] + fc_b[n]; h periodic-32 ->
    // mask to lanes 0..31 to avoid double counting
    float wv0 = fcw[lane & 31];
    float wv1 = fcw[32 + (lane & 31)];
    float p0v = (lane < 32) ? h * wv0 : 0.0f;
    float p1v = (lane < 32) ? h * wv1 : 0.0f;
#pragma unroll
    for (int m = 32; m >= 1; m >>= 1) {
        p0v += __shfl_xor(p0v, m, 64);
        p1v += __shfl_xor(p1v, m, 64);
    }
    if (lane == 0) {
        out[b * 2 + 0] = p0v + fcb[0];
        out[b * 2 + 1] = p1v + fcb[1];
    }
}

extern "C" void kernel_launch(void* const* d_in, const int* in_sizes, int n_in,
                              void* d_out, int out_size, void* d_ws, size_t ws_size,
                              hipStream_t stream) {
    const int* x = (const int*)d_in[0];
    const float* emb = (const float*)d_in[1];
    const float* wih = (const float*)d_in[2];
    const float* whh = (const float*)d_in[3];
    const float* bih = (const float*)d_in[4];
    const float* bhh = (const float*)d_in[5];
    const float* fcw = (const float*)d_in[6];
    const float* fcb = (const float*)d_in[7];
    float* out = (float*)d_out;

    const int B = out_size / 2;          // 1024
    const int S = in_sizes[0] / B;       // 512
    const int nrows = in_sizes[1] / 32;  // 50001 (EMB=32)

    const size_t need = (size_t)nrows * 64 * sizeof(float2);  // 25.6 MB
    const size_t smem = (size_t)(S + 16) * sizeof(int);

    if (ws_size >= need) {
        float2* ptab = (float2*)d_ws;
        int nb = nrows < 8192 ? nrows : 8192;
        build_ptab<<<nb, 64, 0, stream>>>((const float4*)emb, (const float4*)wih,
                                          bih, bhh, ptab, nrows);
        lstm_scan<true><<<B, 64, smem, stream>>>(x, ptab, emb, wih, bih, bhh, whh,
                                                 fcw, fcb, out, S);
    } else {
        lstm_scan<false><<<B, 64, smem, stream>>>(x, nullptr, emb, wih, bih, bhh, whh,
                                                  fcw, fcb, out, S);
    }
}